// Round 5
// baseline (843.108 us; speedup 1.0000x reference)
//
#include <hip/hip_runtime.h>

typedef unsigned short u16;
typedef __bf16 bf8v __attribute__((ext_vector_type(8)));
typedef float f32x4 __attribute__((ext_vector_type(4)));

#define N_ATOMS 524288
#define NROW32  16777216  // N_ATOMS * 32

__device__ __forceinline__ float b2f(u16 u) {
  return __builtin_bit_cast(float, ((unsigned)u) << 16);
}
__device__ __forceinline__ u16 f2b(float f) {
  unsigned x = __builtin_bit_cast(unsigned, f);
  x += 0x7fffu + ((x >> 16) & 1u);   // RNE
  return (u16)(x >> 16);
}

// dtype-agnostic loads: isbf=1 -> buffer is packed bf16 (u16), else float32
__device__ __forceinline__ float ldf(const void* p, size_t i, int isbf) {
  return isbf ? b2f(((const u16*)p)[i]) : ((const float*)p)[i];
}
__device__ __forceinline__ u16 ldb(const void* p, size_t i, int isbf) {
  return isbf ? ((const u16*)p)[i] : f2b(((const float*)p)[i]);
}

// degree segment of row r; boundaries are multiples of 64 so 64-row blocks are uniform
__device__ __forceinline__ void seg_of(int r, int& d, int& off) {
  if      (r < 8192)   { d = 0; off = 0; }
  else if (r < 73728)  { d = 1; off = 8192; }
  else if (r < 204800) { d = 2; off = 73728; }
  else if (r < 401408) { d = 3; off = 204800; }
  else if (r < 499712) { d = 4; off = 401408; }
  else if (r < 516096) { d = 5; off = 499712; }
  else                 { d = 6; off = 516096; }
}

// ---------------- dtype probe (writes 1/0 to flag[0])
__global__ void probe_kernel(const void* __restrict__ atoms, int* __restrict__ flag) {
  int lane = threadIdx.x;                       // 64 threads
  unsigned u = ((const u16*)atoms)[(size_t)lane * 148];   // even indices, spread out
  int e = (u >> 7) & 0xFF;
  bool ok = (e >= 100 && e <= 140);
  unsigned long long b = __ballot(ok);
  if (lane == 0) flag[0] = (__popcll(b) >= 48) ? 1 : 0;
}

// ---------------- convert: atoms (fp32 or bf16, 75 cols) -> bf16 80-col padded
__global__ __launch_bounds__(256) void convert_kernel(
    const void* __restrict__ atoms, const int* flagp, u16* __restrict__ outB)
{
  __shared__ __align__(16) u16 sT[128 * 80];   // 20 KB
  const int isbf = flagp[0];
  const int tid = threadIdx.x;
  const int rb = blockIdx.x * 128;

  for (int i = tid; i < 128 * 5; i += 256) {
    int rl = i / 5, k = 75 + (i % 5);
    sT[rl * 80 + k] = 0;
  }

  if (isbf) {
    const uint4* in4 = (const uint4*)((const u16*)atoms + (size_t)rb * 75);
    for (int i = tid; i < 1200; i += 256) {     // 9600 u16 = 1200 x 8
      uint4 v = in4[i];
      union { uint4 u4; u16 us[8]; } w; w.u4 = v;
      int e0 = i * 8;
      #pragma unroll
      for (int j = 0; j < 8; ++j) {
        int e = e0 + j, rl = e / 75, k = e - rl * 75;
        sT[rl * 80 + k] = w.us[j];
      }
    }
  } else {
    const f32x4* in4 = (const f32x4*)((const float*)atoms + (size_t)rb * 75);
    for (int i = tid; i < 2400; i += 256) {     // 9600 f32 = 2400 x 4
      f32x4 v = in4[i];
      int e0 = i * 4;
      #pragma unroll
      for (int j = 0; j < 4; ++j) {
        int e = e0 + j, rl = e / 75, k = e - rl * 75;
        sT[rl * 80 + k] = f2b(v[j]);
      }
    }
  }
  __syncthreads();

  uint4* dst = (uint4*)(outB + (size_t)rb * 80);
  const uint4* src = (const uint4*)sT;
  for (int i = tid; i < 1280; i += 256) dst[i] = src[i];
}

// ---------------- conv1: A-fragments gathered straight from global (no LDS)
// lane (nl,q) of wave wvid owns row r = rb + wvid*16 + nl; fragment ks covers
// k = ks*32 + q*8 .. +8  in the K=160 layout [rel 80 | self 80].
template<int D>
__device__ __forceinline__ void gather_frags_conv1(
    const u16* __restrict__ atomsB, const int* __restrict__ adjp,
    int r, int off, int q, bf8v afrag[5])
{
  constexpr int DD = (D > 0) ? D : 1;
  int nb[DD];
  if (D > 0) {
    size_t ib = (size_t)(r - off) * D;
    #pragma unroll
    for (int j = 0; j < D; ++j) nb[j] = adjp[ib + j];
  }
  const u16* selfp = atomsB + (size_t)r * 80;
  #pragma unroll
  for (int ks = 0; ks < 5; ++ks) {
    const int c = ks * 32 + q * 8;
    if (c >= 80) {                       // self chunk: load bf16 as-is
      afrag[ks] = *(const bf8v*)(selfp + (c - 80));
    } else {                             // rel chunk: sum over D neighbors
      uint4 nv[DD];
      #pragma unroll
      for (int j = 0; j < D; ++j)
        nv[j] = *(const uint4*)(atomsB + (size_t)nb[j] * 80 + c);
      float rs[8];
      #pragma unroll
      for (int i = 0; i < 8; ++i) rs[i] = 0.f;
      #pragma unroll
      for (int j = 0; j < D; ++j) {
        union { uint4 u4; u16 us[8]; } a; a.u4 = nv[j];
        #pragma unroll
        for (int i = 0; i < 8; ++i) rs[i] += b2f(a.us[i]);
      }
      union { u16 us[8]; bf8v v; } o;
      #pragma unroll
      for (int i = 0; i < 8; ++i) o.us[i] = f2b(rs[i]);
      afrag[ks] = o.v;
    }
  }
}

__global__ __launch_bounds__(256) void conv1_fast_kernel(
    const u16* __restrict__ atomsB, const void* __restrict__ gW, const void* __restrict__ gB,
    const void* __restrict__ bng, const void* __restrict__ bnb,
    const void* __restrict__ bnm, const void* __restrict__ bnv,
    const int* __restrict__ a1, const int* __restrict__ a2, const int* __restrict__ a3,
    const int* __restrict__ a4, const int* __restrict__ a5, const int* __restrict__ a6,
    const int* flagp, u16* __restrict__ out)
{
  const int isbf = flagp[0];
  const int tid = threadIdx.x;
  const int rb = blockIdx.x * 64;
  int d, off; seg_of(rb, d, off);
  const int wr  = (d == 0) ? 12 : 2 * (d - 1);
  const int wsi = (d == 0) ? 12 : 2 * (d - 1) + 1;
  const size_t wrb = (size_t)wr  * 2400;
  const size_t wsb = (size_t)wsi * 2400;
  const int lane = tid & 63;
  const int nl = lane & 15;
  const int q  = lane >> 4;
  const int wvid = tid >> 6;
  const int r = rb + wvid * 16 + nl;

  // weight (B-operand) fragments: B[k][n], n = ct*16+nl, k = ks*32 + q*8 + j
  bf8v bfrag[5][2];
  #pragma unroll
  for (int ks = 0; ks < 5; ++ks) {
    #pragma unroll
    for (int ct = 0; ct < 2; ++ct) {
      union { u16 u[8]; bf8v v; } tmp;
      #pragma unroll
      for (int j = 0; j < 8; ++j) {
        int k = ks * 32 + q * 8 + j;
        int n = ct * 16 + nl;
        u16 val = 0;
        if (k < 75) val = ldb(gW, wrb + (size_t)k * 32 + n, isbf);
        else if (k >= 80 && k < 155) val = ldb(gW, wsb + (size_t)(k - 80) * 32 + n, isbf);
        tmp.u[j] = val;
      }
      bfrag[ks][ct] = tmp.v;
    }
  }

  bf8v afrag[5];
  switch (d) {
    case 0: gather_frags_conv1<0>(atomsB, a1, r, off, q, afrag); break;
    case 1: gather_frags_conv1<1>(atomsB, a1, r, off, q, afrag); break;
    case 2: gather_frags_conv1<2>(atomsB, a2, r, off, q, afrag); break;
    case 3: gather_frags_conv1<3>(atomsB, a3, r, off, q, afrag); break;
    case 4: gather_frags_conv1<4>(atomsB, a4, r, off, q, afrag); break;
    case 5: gather_frags_conv1<5>(atomsB, a5, r, off, q, afrag); break;
    default: gather_frags_conv1<6>(atomsB, a6, r, off, q, afrag); break;
  }

  f32x4 acc0 = {0.f, 0.f, 0.f, 0.f};
  f32x4 acc1 = {0.f, 0.f, 0.f, 0.f};
  #pragma unroll
  for (int ks = 0; ks < 5; ++ks) {
    acc0 = __builtin_amdgcn_mfma_f32_16x16x32_bf16(afrag[ks], bfrag[ks][0], acc0, 0, 0, 0);
    acc1 = __builtin_amdgcn_mfma_f32_16x16x32_bf16(afrag[ks], bfrag[ks][1], acc1, 0, 0, 0);
  }

  #pragma unroll
  for (int ct = 0; ct < 2; ++ct) {
    f32x4 acc = ct ? acc1 : acc0;
    int col = ct * 16 + nl;
    float bias = (d == 0) ? ldf(gB, 12 * 32 + col, isbf)
                          : ldf(gB, wr * 32 + col, isbf) + ldf(gB, wsi * 32 + col, isbf);
    float g  = ldf(bng, col, isbf);
    float be = ldf(bnb, col, isbf);
    float mn = ldf(bnm, col, isbf);
    float inv = 1.0f / sqrtf(ldf(bnv, col, isbf) + 0.001f);
    #pragma unroll
    for (int reg = 0; reg < 4; ++reg) {
      int row = rb + wvid * 16 + q * 4 + reg;
      float t = tanhf(acc[reg] + bias);
      out[(size_t)row * 32 + col] = f2b(g * (t - mn) * inv + be);
    }
  }
}

// ---------------- conv1 slow (fallback when ws_size too small)
__global__ __launch_bounds__(256) void conv1_slow_kernel(
    const void* __restrict__ atoms, const void* __restrict__ gW, const void* __restrict__ gB,
    const void* __restrict__ bng, const void* __restrict__ bnb,
    const void* __restrict__ bnm, const void* __restrict__ bnv,
    const int* __restrict__ a1, const int* __restrict__ a2, const int* __restrict__ a3,
    const int* __restrict__ a4, const int* __restrict__ a5, const int* __restrict__ a6,
    const int* flagp, u16* __restrict__ out)
{
  __shared__ __align__(16) u16 sX[64 * 168];
  const int isbf = flagp[0];
  const int tid = threadIdx.x;
  const int rb = blockIdx.x * 64;
  int d, off; seg_of(rb, d, off);
  const int wr  = (d == 0) ? 12 : 2 * (d - 1);
  const int wsi = (d == 0) ? 12 : 2 * (d - 1) + 1;
  const size_t wrb = (size_t)wr  * 2400;
  const size_t wsb = (size_t)wsi * 2400;
  const int lane = tid & 63;
  const int nl = lane & 15;
  const int q  = lane >> 4;

  bf8v bfrag[5][2];
  #pragma unroll
  for (int ks = 0; ks < 5; ++ks) {
    #pragma unroll
    for (int ct = 0; ct < 2; ++ct) {
      union { u16 u[8]; bf8v v; } tmp;
      #pragma unroll
      for (int j = 0; j < 8; ++j) {
        int k = ks * 32 + q * 8 + j;
        int n = ct * 16 + nl;
        u16 val = 0;
        if (k < 75) val = ldb(gW, wrb + (size_t)k * 32 + n, isbf);
        else if (k >= 80 && k < 155) val = ldb(gW, wsb + (size_t)(k - 80) * 32 + n, isbf);
        tmp.u[j] = val;
      }
      bfrag[ks][ct] = tmp.v;
    }
  }

  {
    const int lr = tid >> 2;
    const int kq = tid & 3;
    const int r  = rb + lr;
    int nb[6];
    if (d > 0) {
      const int* adjp = (d==1)?a1:(d==2)?a2:(d==3)?a3:(d==4)?a4:(d==5)?a5:a6;
      size_t ib = (size_t)(r - off) * d;
      for (int j = 0; j < d; ++j) nb[j] = adjp[ib + j];
    }
    u16* px = sX + lr * 168;
    for (int k = kq; k < 80; k += 4) {
      u16 sv = 0; float rs = 0.f;
      if (k < 75) {
        sv = ldb(atoms, (size_t)r * 75 + k, isbf);
        for (int j = 0; j < d; ++j) rs += ldf(atoms, (size_t)nb[j] * 75 + k, isbf);
      }
      px[80 + k] = sv;
      px[k]      = f2b(rs);
    }
  }
  __syncthreads();

  const int wvid = tid >> 6;
  f32x4 acc0 = {0.f, 0.f, 0.f, 0.f};
  f32x4 acc1 = {0.f, 0.f, 0.f, 0.f};
  const u16* abase = sX + (wvid * 16 + nl) * 168 + q * 8;
  #pragma unroll
  for (int ks = 0; ks < 5; ++ks) {
    bf8v a = *(const bf8v*)(abase + ks * 32);
    acc0 = __builtin_amdgcn_mfma_f32_16x16x32_bf16(a, bfrag[ks][0], acc0, 0, 0, 0);
    acc1 = __builtin_amdgcn_mfma_f32_16x16x32_bf16(a, bfrag[ks][1], acc1, 0, 0, 0);
  }

  #pragma unroll
  for (int ct = 0; ct < 2; ++ct) {
    f32x4 acc = ct ? acc1 : acc0;
    int col = ct * 16 + nl;
    float bias = (d == 0) ? ldf(gB, 12 * 32 + col, isbf)
                          : ldf(gB, wr * 32 + col, isbf) + ldf(gB, wsi * 32 + col, isbf);
    float g  = ldf(bng, col, isbf);
    float be = ldf(bnb, col, isbf);
    float mn = ldf(bnm, col, isbf);
    float inv = 1.0f / sqrtf(ldf(bnv, col, isbf) + 0.001f);
    #pragma unroll
    for (int reg = 0; reg < 4; ++reg) {
      int row = rb + wvid * 16 + q * 4 + reg;
      float t = tanhf(acc[reg] + bias);
      out[(size_t)row * 32 + col] = f2b(g * (t - mn) * inv + be);
    }
  }
}

// ---------------- conv2: direct A-fragment gather, K = 64 = [rel 32 | self 32]
template<int D>
__device__ __forceinline__ void gather_frags_conv2(
    const u16* __restrict__ in, const int* __restrict__ adjp,
    int r, int off, int q, bf8v afrag[2])
{
  constexpr int DD = (D > 0) ? D : 1;
  int nb[DD];
  if (D > 0) {
    size_t ib = (size_t)(r - off) * D;
    #pragma unroll
    for (int j = 0; j < D; ++j) nb[j] = adjp[ib + j];
  }
  afrag[1] = *(const bf8v*)(in + (size_t)r * 32 + q * 8);   // self (ks=1)
  uint4 nv[DD];
  #pragma unroll
  for (int j = 0; j < D; ++j)
    nv[j] = *(const uint4*)(in + (size_t)nb[j] * 32 + q * 8);
  float rs[8];
  #pragma unroll
  for (int i = 0; i < 8; ++i) rs[i] = 0.f;
  #pragma unroll
  for (int j = 0; j < D; ++j) {
    union { uint4 u4; u16 us[8]; } a; a.u4 = nv[j];
    #pragma unroll
    for (int i = 0; i < 8; ++i) rs[i] += b2f(a.us[i]);
  }
  union { u16 us[8]; bf8v v; } o;
  #pragma unroll
  for (int i = 0; i < 8; ++i) o.us[i] = f2b(rs[i]);
  afrag[0] = o.v;                                            // rel (ks=0)
}

__global__ __launch_bounds__(256) void conv2_kernel(
    const u16* __restrict__ in, const void* __restrict__ gW, const void* __restrict__ gB,
    const void* __restrict__ bng, const void* __restrict__ bnb,
    const void* __restrict__ bnm, const void* __restrict__ bnv,
    const int* __restrict__ a1, const int* __restrict__ a2, const int* __restrict__ a3,
    const int* __restrict__ a4, const int* __restrict__ a5, const int* __restrict__ a6,
    const int* flagp, u16* __restrict__ out)
{
  const int isbf = flagp[0];
  const int tid = threadIdx.x;
  const int rb = blockIdx.x * 64;
  int d, off; seg_of(rb, d, off);
  const int wr  = (d == 0) ? 12 : 2 * (d - 1);
  const int wsi = (d == 0) ? 12 : 2 * (d - 1) + 1;
  const size_t wrb = (size_t)wr  * 1024;
  const size_t wsb = (size_t)wsi * 1024;
  const int lane = tid & 63;
  const int nl = lane & 15;
  const int q  = lane >> 4;
  const int wvid = tid >> 6;
  const int r = rb + wvid * 16 + nl;

  bf8v bfrag[2][2];
  #pragma unroll
  for (int ks = 0; ks < 2; ++ks) {
    #pragma unroll
    for (int ct = 0; ct < 2; ++ct) {
      union { u16 u[8]; bf8v v; } tmp;
      #pragma unroll
      for (int j = 0; j < 8; ++j) {
        int k = ks * 32 + q * 8 + j;
        int n = ct * 16 + nl;
        tmp.u[j] = (k < 32) ? ldb(gW, wrb + (size_t)k * 32 + n, isbf)
                            : ldb(gW, wsb + (size_t)(k - 32) * 32 + n, isbf);
      }
      bfrag[ks][ct] = tmp.v;
    }
  }

  bf8v afrag[2];
  switch (d) {
    case 0: gather_frags_conv2<0>(in, a1, r, off, q, afrag); break;
    case 1: gather_frags_conv2<1>(in, a1, r, off, q, afrag); break;
    case 2: gather_frags_conv2<2>(in, a2, r, off, q, afrag); break;
    case 3: gather_frags_conv2<3>(in, a3, r, off, q, afrag); break;
    case 4: gather_frags_conv2<4>(in, a4, r, off, q, afrag); break;
    case 5: gather_frags_conv2<5>(in, a5, r, off, q, afrag); break;
    default: gather_frags_conv2<6>(in, a6, r, off, q, afrag); break;
  }

  f32x4 acc0 = {0.f, 0.f, 0.f, 0.f};
  f32x4 acc1 = {0.f, 0.f, 0.f, 0.f};
  #pragma unroll
  for (int ks = 0; ks < 2; ++ks) {
    acc0 = __builtin_amdgcn_mfma_f32_16x16x32_bf16(afrag[ks], bfrag[ks][0], acc0, 0, 0, 0);
    acc1 = __builtin_amdgcn_mfma_f32_16x16x32_bf16(afrag[ks], bfrag[ks][1], acc1, 0, 0, 0);
  }

  #pragma unroll
  for (int ct = 0; ct < 2; ++ct) {
    f32x4 acc = ct ? acc1 : acc0;
    int col = ct * 16 + nl;
    float bias = (d == 0) ? ldf(gB, 12 * 32 + col, isbf)
                          : ldf(gB, wr * 32 + col, isbf) + ldf(gB, wsi * 32 + col, isbf);
    float g  = ldf(bng, col, isbf);
    float be = ldf(bnb, col, isbf);
    float mn = ldf(bnm, col, isbf);
    float inv = 1.0f / sqrtf(ldf(bnv, col, isbf) + 0.001f);
    #pragma unroll
    for (int reg = 0; reg < 4; ++reg) {
      int row = rb + wvid * 16 + q * 4 + reg;
      float t = tanhf(acc[reg] + bias);
      out[(size_t)row * 32 + col] = f2b(g * (t - mn) * inv + be);
    }
  }
}

// ---------------- graph pool: 1 thread per 8 channels, all loads upfront
template<int D>
__device__ __forceinline__ void pool_one(
    const u16* __restrict__ in, const int* __restrict__ adjp,
    int r, int off, int q8, u16* __restrict__ out)
{
  constexpr int DD = (D > 0) ? D : 1;
  int nb[DD];
  if (D > 0) {
    size_t ib = (size_t)(r - off) * D;
    #pragma unroll
    for (int j = 0; j < D; ++j) nb[j] = adjp[ib + j];
  }
  uint4 sv = *(const uint4*)(in + (size_t)r * 32 + q8);
  uint4 nv[DD];
  #pragma unroll
  for (int j = 0; j < D; ++j) nv[j] = *(const uint4*)(in + (size_t)nb[j] * 32 + q8);
  union { uint4 u4; u16 us[8]; } s; s.u4 = sv;
  float v[8];
  #pragma unroll
  for (int i = 0; i < 8; ++i) v[i] = b2f(s.us[i]);
  #pragma unroll
  for (int j = 0; j < D; ++j) {
    union { uint4 u4; u16 us[8]; } a; a.u4 = nv[j];
    #pragma unroll
    for (int i = 0; i < 8; ++i) v[i] = fmaxf(v[i], b2f(a.us[i]));
  }
  union { uint4 u4; u16 us[8]; } o;
  #pragma unroll
  for (int i = 0; i < 8; ++i) o.us[i] = f2b(v[i]);
  *(uint4*)(out + (size_t)r * 32 + q8) = o.u4;
}

__global__ __launch_bounds__(256) void pool_kernel(
    const u16* __restrict__ in, u16* __restrict__ out,
    const int* __restrict__ a1, const int* __restrict__ a2, const int* __restrict__ a3,
    const int* __restrict__ a4, const int* __restrict__ a5, const int* __restrict__ a6)
{
  int idx = blockIdx.x * 256 + threadIdx.x;   // N_ATOMS*4 threads
  int r = idx >> 2, q8 = (idx & 3) * 8;
  int d, off; seg_of(r, d, off);
  switch (d) {
    case 0: pool_one<0>(in, a1, r, off, q8, out); break;
    case 1: pool_one<1>(in, a1, r, off, q8, out); break;
    case 2: pool_one<2>(in, a2, r, off, q8, out); break;
    case 3: pool_one<3>(in, a3, r, off, q8, out); break;
    case 4: pool_one<4>(in, a4, r, off, q8, out); break;
    case 5: pool_one<5>(in, a5, r, off, q8, out); break;
    default: pool_one<6>(in, a6, r, off, q8, out); break;
  }
}

// ---------------- head: 4 molecules per 256-thread block
__global__ __launch_bounds__(256) void head_kernel(
    const u16* __restrict__ in, const void* __restrict__ d1W, const void* __restrict__ d1b,
    const void* __restrict__ g3, const void* __restrict__ b3,
    const void* __restrict__ m3, const void* __restrict__ v3,
    const void* __restrict__ d2W, const void* __restrict__ d2b,
    const void* __restrict__ d3W, const void* __restrict__ d3b,
    const void* __restrict__ xadd, const int* flagp, void* __restrict__ outp)
{
  __shared__ __align__(16) float sA[4][1024];   // per-wave: 32 atoms x 32 features
  const int isbf = flagp[0];
  const int wvid = threadIdx.x >> 6;
  const int m = blockIdx.x * 4 + wvid;
  const int j = threadIdx.x & 63;               // channel 0..63

  #pragma unroll
  for (int ii = 0; ii < 2; ++ii) {
    int i = j + ii * 64;                        // 128 uint4 per molecule
    int t = i >> 2, kq8 = (i & 3) * 8;
    union { uint4 u4; u16 us[8]; } w;
    w.u4 = *(const uint4*)(in + (size_t)(m + t * 16384) * 32 + kq8);
    #pragma unroll
    for (int x = 0; x < 8; ++x) sA[wvid][t * 32 + kq8 + x] = b2f(w.us[x]);
  }
  __syncthreads();

  float wcol[32];
  #pragma unroll
  for (int k = 0; k < 32; ++k) wcol[k] = ldf(d1W, k * 64 + j, isbf);
  const float bj = ldf(d1b, j, isbf);
  const float g  = ldf(g3, j, isbf);
  const float bt = ldf(b3, j, isbf);
  const float mn = ldf(m3, j, isbf);
  const float inv = 1.0f / sqrtf(ldf(v3, j, isbf) + 0.001f);

  float sum = 0.f, mx = -1e30f;
  for (int t = 0; t < 32; ++t) {
    const f32x4* arow = (const f32x4*)(&sA[wvid][t * 32]);
    float dot = bj;
    #pragma unroll
    for (int k4 = 0; k4 < 8; ++k4) {
      f32x4 av = arow[k4];
      dot += av[0] * wcol[k4 * 4]     + av[1] * wcol[k4 * 4 + 1]
           + av[2] * wcol[k4 * 4 + 2] + av[3] * wcol[k4 * 4 + 3];
    }
    float h  = tanhf(dot);
    float hb = g * (h - mn) * inv + bt;
    sum += hb;
    mx = fmaxf(mx, hb);
  }

  float part = tanhf(sum) * ldf(d2W, j, isbf) + tanhf(mx) * ldf(d2W, 64 + j, isbf);
  #pragma unroll
  for (int o = 32; o > 0; o >>= 1) part += __shfl_down(part, o, 64);

  if (j == 0) {
    float mv  = part + ldf(d2b, 0, isbf);
    float ans = mv * ldf(d3W, 0, isbf) + ldf(d3b, 0, isbf);
    #pragma unroll
    for (int i = 0; i < 15; ++i) ans += ldf(xadd, m * 15 + i, isbf) * ldf(d3W, 1 + i, isbf);
    if (isbf) ((u16*)outp)[m] = f2b(ans);
    else      ((float*)outp)[m] = ans;
  }
}

extern "C" void kernel_launch(void* const* d_in, const int* in_sizes, int n_in,
                              void* d_out, int out_size, void* d_ws, size_t ws_size,
                              hipStream_t stream)
{
  (void)in_sizes; (void)n_in; (void)out_size;
  const void* atoms = d_in[0];
  const int* a1 = (const int*)d_in[2];
  const int* a2 = (const int*)d_in[3];
  const int* a3 = (const int*)d_in[4];
  const int* a4 = (const int*)d_in[5];
  const int* a5 = (const int*)d_in[6];
  const int* a6 = (const int*)d_in[7];

  int* flag = (int*)d_ws;                       // 256-byte header
  u16* buf0 = (u16*)d_ws + 128;                 // 32 MB

  // fast path needs: 256 B + buf0 (32 MB) + atomsB (84 MB); buf1 aliases atomsB
  const size_t need = 256 + (size_t)NROW32 * 2 + (size_t)N_ATOMS * 80 * 2;
  const bool fast = ws_size >= need;

  probe_kernel<<<1, 64, 0, stream>>>(atoms, flag);

  u16* buf1;
  if (fast) {
    u16* atomsB = buf0 + NROW32;                // 84 MB region
    buf1 = atomsB;                              // aliased: atomsB dead after conv1
    convert_kernel<<<4096, 256, 0, stream>>>(atoms, flag, atomsB);
    conv1_fast_kernel<<<8192, 256, 0, stream>>>(atomsB, d_in[8], d_in[9], d_in[12],
                                                d_in[13], d_in[14], d_in[15],
                                                a1, a2, a3, a4, a5, a6, flag, buf0);
  } else {
    buf1 = buf0 + NROW32;
    conv1_slow_kernel<<<8192, 256, 0, stream>>>(atoms, d_in[8], d_in[9], d_in[12],
                                                d_in[13], d_in[14], d_in[15],
                                                a1, a2, a3, a4, a5, a6, flag, buf0);
  }

  pool_kernel<<<8192, 256, 0, stream>>>(buf0, buf1, a1, a2, a3, a4, a5, a6);
  conv2_kernel<<<8192, 256, 0, stream>>>(buf1, d_in[10], d_in[11], d_in[12], d_in[13],
                                         d_in[14], d_in[15], a1, a2, a3, a4, a5, a6,
                                         flag, buf0);
  pool_kernel<<<8192, 256, 0, stream>>>(buf0, buf1, a1, a2, a3, a4, a5, a6);
  head_kernel<<<4096, 256, 0, stream>>>(buf1, d_in[20], d_in[21], d_in[16], d_in[17],
                                        d_in[18], d_in[19], d_in[22], d_in[23],
                                        d_in[24], d_in[25], d_in[26], flag, d_out);
}

// Round 6
// 556.510 us; speedup vs baseline: 1.5150x; 1.5150x over previous
//
#include <hip/hip_runtime.h>

typedef unsigned short u16;
typedef __bf16 bf8v __attribute__((ext_vector_type(8)));
typedef float f32x4 __attribute__((ext_vector_type(4)));

#define N_ATOMS 524288
#define NROW32  16777216  // N_ATOMS * 32

// ---- d_ws layout (bytes) ----
// 0      : int flag
// 256    : float P[3090]  (ep1[224] ep2@224 bn1@448 bn3@576 d1wt@832 d1b@2880 d2w@2944 sc@3072)
// 16384  : u16 wf1[7][5][2][64][8]   (71680 B)  conv1 B-fragments per degree
// 88064  : u16 wf2[7][2][2][64][8]   (28672 B)  conv2 B-fragments per degree
// 131072 : u16 buf0[NROW32]          (32 MB)
// 131072+32M : u16 atomsB/buf1       (84 MB)
#define P_EP1   0
#define P_EP2   224
#define P_BN1   448
#define P_BN3   576
#define P_D1WT  832
#define P_D1B   2880
#define P_D2W   2944
#define P_SC    3072

__device__ __forceinline__ float b2f(u16 u) {
  return __builtin_bit_cast(float, ((unsigned)u) << 16);
}
__device__ __forceinline__ u16 f2b(float f) {
  unsigned x = __builtin_bit_cast(unsigned, f);
  x += 0x7fffu + ((x >> 16) & 1u);   // RNE
  return (u16)(x >> 16);
}
__device__ __forceinline__ float ldf(const void* p, size_t i, int isbf) {
  return isbf ? b2f(((const u16*)p)[i]) : ((const float*)p)[i];
}
__device__ __forceinline__ u16 ldb(const void* p, size_t i, int isbf) {
  return isbf ? ((const u16*)p)[i] : f2b(((const float*)p)[i]);
}

__device__ __forceinline__ float exp2_fast(float x) {
#if __has_builtin(__builtin_amdgcn_exp2f)
  return __builtin_amdgcn_exp2f(x);
#else
  return exp2f(x);
#endif
}
__device__ __forceinline__ float rcp_fast(float x) {
#if __has_builtin(__builtin_amdgcn_rcpf)
  return __builtin_amdgcn_rcpf(x);
#else
  return 1.0f / x;
#endif
}
// tanh via hw exp2: tanh(x) = (1 - e^{-2x}) / (1 + e^{-2x})
__device__ __forceinline__ float tanh_fast(float x) {
  float xc = fminf(fmaxf(x, -15.f), 15.f);
  float t = exp2_fast(xc * -2.8853900817779268f);
  return (1.f - t) * rcp_fast(1.f + t);
}

// degree segment of row r; boundaries are multiples of 128 so 128-row blocks are uniform
__device__ __forceinline__ void seg_of(int r, int& d, int& off) {
  if      (r < 8192)   { d = 0; off = 0; }
  else if (r < 73728)  { d = 1; off = 8192; }
  else if (r < 204800) { d = 2; off = 73728; }
  else if (r < 401408) { d = 3; off = 204800; }
  else if (r < 499712) { d = 4; off = 401408; }
  else if (r < 516096) { d = 5; off = 499712; }
  else                 { d = 6; off = 516096; }
}

// ---------------- dtype probe (writes 1/0 to flag[0])
__global__ void probe_kernel(const void* __restrict__ atoms, int* __restrict__ flag) {
  int lane = threadIdx.x;                       // 64 threads
  unsigned u = ((const u16*)atoms)[(size_t)lane * 148];
  int e = (u >> 7) & 0xFF;
  bool ok = (e >= 100 && e <= 140);
  unsigned long long b = __ballot(ok);
  if (lane == 0) flag[0] = (__popcll(b) >= 48) ? 1 : 0;
}

// ---------------- prep: build weight fragments + fused param tables (one-time)
__global__ __launch_bounds__(64) void prep_kernel(
    const void* gW1, const void* gB1, const void* gW2, const void* gB2,
    const void* b1g, const void* b1b, const void* b1m, const void* b1v,
    const void* g3, const void* b3, const void* m3, const void* v3,
    const void* d1W, const void* d1b, const void* d2W, const void* d2b,
    const void* d3W, const void* d3b,
    const int* flagp, char* ws)
{
  const int isbf = flagp[0];
  const int lane = threadIdx.x;
  float* P  = (float*)(ws + 256);
  u16* wf1 = (u16*)(ws + 16384);
  u16* wf2 = (u16*)(ws + 88064);
  const int blk = blockIdx.x;

  if (blk < 7) {
    const int d = blk;
    const int wr  = (d == 0) ? 12 : 2 * (d - 1);
    const int wsi = (d == 0) ? 12 : 2 * (d - 1) + 1;
    const int nl = lane & 15, q = lane >> 4;
    // conv1 fragments: B[k][n], k = ks*32+q*8+j in [rel75|pad5|self75|pad5]
    #pragma unroll
    for (int ks = 0; ks < 5; ++ks)
      #pragma unroll
      for (int ct = 0; ct < 2; ++ct) {
        u16* dst = wf1 + (size_t)(((d * 5 + ks) * 2 + ct) * 64 + lane) * 8;
        #pragma unroll
        for (int j = 0; j < 8; ++j) {
          int k = ks * 32 + q * 8 + j, n = ct * 16 + nl;
          u16 val = 0;
          if (k < 75) val = ldb(gW1, (size_t)wr * 2400 + k * 32 + n, isbf);
          else if (k >= 80 && k < 155) val = ldb(gW1, (size_t)wsi * 2400 + (k - 80) * 32 + n, isbf);
          dst[j] = val;
        }
      }
    // conv2 fragments: K=64 [rel32|self32]
    #pragma unroll
    for (int ks = 0; ks < 2; ++ks)
      #pragma unroll
      for (int ct = 0; ct < 2; ++ct) {
        u16* dst = wf2 + (size_t)(((d * 2 + ks) * 2 + ct) * 64 + lane) * 8;
        #pragma unroll
        for (int j = 0; j < 8; ++j) {
          int k = ks * 32 + q * 8 + j, n = ct * 16 + nl;
          dst[j] = (k < 32) ? ldb(gW2, (size_t)wr * 1024 + k * 32 + n, isbf)
                            : ldb(gW2, (size_t)wsi * 1024 + (k - 32) * 32 + n, isbf);
        }
      }
    if (lane < 32) {
      int col = lane;
      float bb1 = (d == 0) ? ldf(gB1, 12 * 32 + col, isbf)
                           : ldf(gB1, wr * 32 + col, isbf) + ldf(gB1, wsi * 32 + col, isbf);
      float bb2 = (d == 0) ? ldf(gB2, 12 * 32 + col, isbf)
                           : ldf(gB2, wr * 32 + col, isbf) + ldf(gB2, wsi * 32 + col, isbf);
      P[P_EP1 + d * 32 + col] = bb1;
      P[P_EP2 + d * 32 + col] = bb2;
    }
  } else {
    if (lane < 32) {
      P[P_BN1 + lane]      = ldf(b1g, lane, isbf);
      P[P_BN1 + 32 + lane] = ldf(b1b, lane, isbf);
      P[P_BN1 + 64 + lane] = ldf(b1m, lane, isbf);
      P[P_BN1 + 96 + lane] = 1.0f / sqrtf(ldf(b1v, lane, isbf) + 0.001f);
    }
    P[P_BN3 + lane]       = ldf(g3, lane, isbf);
    P[P_BN3 + 64 + lane]  = ldf(b3, lane, isbf);
    P[P_BN3 + 128 + lane] = ldf(m3, lane, isbf);
    P[P_BN3 + 192 + lane] = 1.0f / sqrtf(ldf(v3, lane, isbf) + 0.001f);
    for (int k = 0; k < 32; ++k)
      P[P_D1WT + lane * 32 + k] = ldf(d1W, k * 64 + lane, isbf);   // transposed
    P[P_D1B + lane] = ldf(d1b, lane, isbf);
    P[P_D2W + lane]      = ldf(d2W, lane, isbf);
    P[P_D2W + 64 + lane] = ldf(d2W, 64 + lane, isbf);
    if (lane < 16) P[P_SC + 1 + lane] = ldf(d3W, lane, isbf);
    if (lane == 0) { P[P_SC] = ldf(d2b, 0, isbf); P[P_SC + 17] = ldf(d3b, 0, isbf); }
  }
}

// ---------------- convert: atoms (fp32 or bf16, 75 cols) -> bf16 80-col padded
__global__ __launch_bounds__(256) void convert_kernel(
    const void* __restrict__ atoms, const int* flagp, u16* __restrict__ outB)
{
  __shared__ __align__(16) u16 sT[128 * 80];
  const int isbf = flagp[0];
  const int tid = threadIdx.x;
  const int rb = blockIdx.x * 128;

  for (int i = tid; i < 128 * 5; i += 256) {
    int rl = i / 5, k = 75 + (i % 5);
    sT[rl * 80 + k] = 0;
  }
  if (isbf) {
    const uint4* in4 = (const uint4*)((const u16*)atoms + (size_t)rb * 75);
    for (int i = tid; i < 1200; i += 256) {
      union { uint4 u4; u16 us[8]; } w; w.u4 = in4[i];
      int e0 = i * 8;
      #pragma unroll
      for (int j = 0; j < 8; ++j) {
        int e = e0 + j, rl = e / 75, k = e - rl * 75;
        sT[rl * 80 + k] = w.us[j];
      }
    }
  } else {
    const f32x4* in4 = (const f32x4*)((const float*)atoms + (size_t)rb * 75);
    for (int i = tid; i < 2400; i += 256) {
      f32x4 v = in4[i];
      int e0 = i * 4;
      #pragma unroll
      for (int j = 0; j < 4; ++j) {
        int e = e0 + j, rl = e / 75, k = e - rl * 75;
        sT[rl * 80 + k] = f2b(v[j]);
      }
    }
  }
  __syncthreads();
  uint4* dst = (uint4*)(outB + (size_t)rb * 80);
  const uint4* src = (const uint4*)sT;
  for (int i = tid; i < 1280; i += 256) dst[i] = src[i];
}

// ---------------- conv1: two 16-row tiles per wave, direct fragment gather
template<int D>
__device__ __forceinline__ void gather2_conv1(
    const u16* __restrict__ atomsB, const int* __restrict__ adjp,
    int r0, int r1, int off, int q, bf8v a0[5], bf8v a1[5])
{
  constexpr int DD = (D > 0) ? D : 1;
  int nb0[DD], nb1[DD];
  if (D > 0) {
    size_t i0 = (size_t)(r0 - off) * D, i1 = (size_t)(r1 - off) * D;
    #pragma unroll
    for (int j = 0; j < D; ++j) { nb0[j] = adjp[i0 + j]; nb1[j] = adjp[i1 + j]; }
  }
  const u16* s0 = atomsB + (size_t)r0 * 80;
  const u16* s1 = atomsB + (size_t)r1 * 80;
  #pragma unroll
  for (int ks = 0; ks < 5; ++ks) {
    const int c = ks * 32 + q * 8;
    if (c >= 80) {
      a0[ks] = *(const bf8v*)(s0 + (c - 80));
      a1[ks] = *(const bf8v*)(s1 + (c - 80));
    } else {
      uint4 v0[DD], v1[DD];
      #pragma unroll
      for (int j = 0; j < D; ++j) {
        v0[j] = *(const uint4*)(atomsB + (size_t)nb0[j] * 80 + c);
        v1[j] = *(const uint4*)(atomsB + (size_t)nb1[j] * 80 + c);
      }
      float r0s[8], r1s[8];
      #pragma unroll
      for (int i = 0; i < 8; ++i) { r0s[i] = 0.f; r1s[i] = 0.f; }
      #pragma unroll
      for (int j = 0; j < D; ++j) {
        union { uint4 u4; u16 us[8]; } a, b;
        a.u4 = v0[j]; b.u4 = v1[j];
        #pragma unroll
        for (int i = 0; i < 8; ++i) { r0s[i] += b2f(a.us[i]); r1s[i] += b2f(b.us[i]); }
      }
      union { u16 us[8]; bf8v v; } o0, o1;
      #pragma unroll
      for (int i = 0; i < 8; ++i) { o0.us[i] = f2b(r0s[i]); o1.us[i] = f2b(r1s[i]); }
      a0[ks] = o0.v; a1[ks] = o1.v;
    }
  }
}

__global__ __launch_bounds__(256) void conv1_fast_kernel(
    const u16* __restrict__ atomsB, const u16* __restrict__ wf1, const float* __restrict__ P,
    const int* __restrict__ a1p, const int* __restrict__ a2p, const int* __restrict__ a3p,
    const int* __restrict__ a4p, const int* __restrict__ a5p, const int* __restrict__ a6p,
    u16* __restrict__ out)
{
  const int tid = threadIdx.x;
  const int rb = blockIdx.x * 128;
  int d, off; seg_of(rb, d, off);
  const int lane = tid & 63;
  const int nl = lane & 15;
  const int q  = lane >> 4;
  const int wvid = tid >> 6;

  bf8v bfrag[5][2];
  #pragma unroll
  for (int ks = 0; ks < 5; ++ks)
    #pragma unroll
    for (int ct = 0; ct < 2; ++ct)
      bfrag[ks][ct] = *(const bf8v*)(wf1 + (size_t)(((d * 5 + ks) * 2 + ct) * 64 + lane) * 8);

  const int r0 = rb + wvid * 32 + nl;
  const int r1 = r0 + 16;
  bf8v a0[5], a1f[5];
  switch (d) {
    case 0: gather2_conv1<0>(atomsB, a1p, r0, r1, off, q, a0, a1f); break;
    case 1: gather2_conv1<1>(atomsB, a1p, r0, r1, off, q, a0, a1f); break;
    case 2: gather2_conv1<2>(atomsB, a2p, r0, r1, off, q, a0, a1f); break;
    case 3: gather2_conv1<3>(atomsB, a3p, r0, r1, off, q, a0, a1f); break;
    case 4: gather2_conv1<4>(atomsB, a4p, r0, r1, off, q, a0, a1f); break;
    case 5: gather2_conv1<5>(atomsB, a5p, r0, r1, off, q, a0, a1f); break;
    default: gather2_conv1<6>(atomsB, a6p, r0, r1, off, q, a0, a1f); break;
  }

  f32x4 acc[2][2] = {{{0,0,0,0},{0,0,0,0}},{{0,0,0,0},{0,0,0,0}}};
  #pragma unroll
  for (int ks = 0; ks < 5; ++ks) {
    acc[0][0] = __builtin_amdgcn_mfma_f32_16x16x32_bf16(a0[ks],  bfrag[ks][0], acc[0][0], 0, 0, 0);
    acc[0][1] = __builtin_amdgcn_mfma_f32_16x16x32_bf16(a0[ks],  bfrag[ks][1], acc[0][1], 0, 0, 0);
    acc[1][0] = __builtin_amdgcn_mfma_f32_16x16x32_bf16(a1f[ks], bfrag[ks][0], acc[1][0], 0, 0, 0);
    acc[1][1] = __builtin_amdgcn_mfma_f32_16x16x32_bf16(a1f[ks], bfrag[ks][1], acc[1][1], 0, 0, 0);
  }

  #pragma unroll
  for (int ct = 0; ct < 2; ++ct) {
    const int col = ct * 16 + nl;
    const float bias = P[P_EP1 + d * 32 + col];
    const float g  = P[P_BN1 + col];
    const float be = P[P_BN1 + 32 + col];
    const float mn = P[P_BN1 + 64 + col];
    const float iv = P[P_BN1 + 96 + col];
    #pragma unroll
    for (int t = 0; t < 2; ++t) {
      #pragma unroll
      for (int reg = 0; reg < 4; ++reg) {
        int row = rb + wvid * 32 + t * 16 + q * 4 + reg;
        float v = tanh_fast(acc[t][ct][reg] + bias);
        out[(size_t)row * 32 + col] = f2b(g * (v - mn) * iv + be);
      }
    }
  }
}

// ---------------- conv1 slow (fallback when ws_size too small) — self-contained
__global__ __launch_bounds__(256) void conv1_slow_kernel(
    const void* __restrict__ atoms, const void* __restrict__ gW, const void* __restrict__ gB,
    const void* __restrict__ bng, const void* __restrict__ bnb,
    const void* __restrict__ bnm, const void* __restrict__ bnv,
    const int* __restrict__ a1, const int* __restrict__ a2, const int* __restrict__ a3,
    const int* __restrict__ a4, const int* __restrict__ a5, const int* __restrict__ a6,
    const int* flagp, u16* __restrict__ out)
{
  __shared__ __align__(16) u16 sX[64 * 168];
  const int isbf = flagp[0];
  const int tid = threadIdx.x;
  const int rb = blockIdx.x * 64;
  int d, off; seg_of(rb, d, off);
  const int wr  = (d == 0) ? 12 : 2 * (d - 1);
  const int wsi = (d == 0) ? 12 : 2 * (d - 1) + 1;
  const size_t wrb = (size_t)wr  * 2400;
  const size_t wsb = (size_t)wsi * 2400;
  const int lane = tid & 63;
  const int nl = lane & 15;
  const int q  = lane >> 4;

  bf8v bfrag[5][2];
  #pragma unroll
  for (int ks = 0; ks < 5; ++ks)
    #pragma unroll
    for (int ct = 0; ct < 2; ++ct) {
      union { u16 u[8]; bf8v v; } tmp;
      #pragma unroll
      for (int j = 0; j < 8; ++j) {
        int k = ks * 32 + q * 8 + j, n = ct * 16 + nl;
        u16 val = 0;
        if (k < 75) val = ldb(gW, wrb + (size_t)k * 32 + n, isbf);
        else if (k >= 80 && k < 155) val = ldb(gW, wsb + (size_t)(k - 80) * 32 + n, isbf);
        tmp.u[j] = val;
      }
      bfrag[ks][ct] = tmp.v;
    }

  {
    const int lr = tid >> 2;
    const int kq = tid & 3;
    const int r  = rb + lr;
    int nb[6];
    if (d > 0) {
      const int* adjp = (d==1)?a1:(d==2)?a2:(d==3)?a3:(d==4)?a4:(d==5)?a5:a6;
      size_t ib = (size_t)(r - off) * d;
      for (int j = 0; j < d; ++j) nb[j] = adjp[ib + j];
    }
    u16* px = sX + lr * 168;
    for (int k = kq; k < 80; k += 4) {
      u16 sv = 0; float rs = 0.f;
      if (k < 75) {
        sv = ldb(atoms, (size_t)r * 75 + k, isbf);
        for (int j = 0; j < d; ++j) rs += ldf(atoms, (size_t)nb[j] * 75 + k, isbf);
      }
      px[80 + k] = sv;
      px[k]      = f2b(rs);
    }
  }
  __syncthreads();

  const int wvid = tid >> 6;
  f32x4 acc0 = {0.f, 0.f, 0.f, 0.f};
  f32x4 acc1 = {0.f, 0.f, 0.f, 0.f};
  const u16* abase = sX + (wvid * 16 + nl) * 168 + q * 8;
  #pragma unroll
  for (int ks = 0; ks < 5; ++ks) {
    bf8v a = *(const bf8v*)(abase + ks * 32);
    acc0 = __builtin_amdgcn_mfma_f32_16x16x32_bf16(a, bfrag[ks][0], acc0, 0, 0, 0);
    acc1 = __builtin_amdgcn_mfma_f32_16x16x32_bf16(a, bfrag[ks][1], acc1, 0, 0, 0);
  }
  #pragma unroll
  for (int ct = 0; ct < 2; ++ct) {
    f32x4 acc = ct ? acc1 : acc0;
    int col = ct * 16 + nl;
    float bias = (d == 0) ? ldf(gB, 12 * 32 + col, isbf)
                          : ldf(gB, wr * 32 + col, isbf) + ldf(gB, wsi * 32 + col, isbf);
    float g  = ldf(bng, col, isbf);
    float be = ldf(bnb, col, isbf);
    float mn = ldf(bnm, col, isbf);
    float iv = 1.0f / sqrtf(ldf(bnv, col, isbf) + 0.001f);
    #pragma unroll
    for (int reg = 0; reg < 4; ++reg) {
      int row = rb + wvid * 16 + q * 4 + reg;
      float t = tanh_fast(acc[reg] + bias);
      out[(size_t)row * 32 + col] = f2b(g * (t - mn) * iv + be);
    }
  }
}

// ---------------- conv2: two tiles per wave, K = 64 = [rel 32 | self 32]
template<int D>
__device__ __forceinline__ void gather2_conv2(
    const u16* __restrict__ in, const int* __restrict__ adjp,
    int r0, int r1, int off, int q, bf8v a0[2], bf8v a1[2])
{
  constexpr int DD = (D > 0) ? D : 1;
  int nb0[DD], nb1[DD];
  if (D > 0) {
    size_t i0 = (size_t)(r0 - off) * D, i1 = (size_t)(r1 - off) * D;
    #pragma unroll
    for (int j = 0; j < D; ++j) { nb0[j] = adjp[i0 + j]; nb1[j] = adjp[i1 + j]; }
  }
  a0[1] = *(const bf8v*)(in + (size_t)r0 * 32 + q * 8);
  a1[1] = *(const bf8v*)(in + (size_t)r1 * 32 + q * 8);
  uint4 v0[DD], v1[DD];
  #pragma unroll
  for (int j = 0; j < D; ++j) {
    v0[j] = *(const uint4*)(in + (size_t)nb0[j] * 32 + q * 8);
    v1[j] = *(const uint4*)(in + (size_t)nb1[j] * 32 + q * 8);
  }
  float r0s[8], r1s[8];
  #pragma unroll
  for (int i = 0; i < 8; ++i) { r0s[i] = 0.f; r1s[i] = 0.f; }
  #pragma unroll
  for (int j = 0; j < D; ++j) {
    union { uint4 u4; u16 us[8]; } a, b;
    a.u4 = v0[j]; b.u4 = v1[j];
    #pragma unroll
    for (int i = 0; i < 8; ++i) { r0s[i] += b2f(a.us[i]); r1s[i] += b2f(b.us[i]); }
  }
  union { u16 us[8]; bf8v v; } o0, o1;
  #pragma unroll
  for (int i = 0; i < 8; ++i) { o0.us[i] = f2b(r0s[i]); o1.us[i] = f2b(r1s[i]); }
  a0[0] = o0.v; a1[0] = o1.v;
}

__global__ __launch_bounds__(256) void conv2_kernel(
    const u16* __restrict__ in, const u16* __restrict__ wf2, const float* __restrict__ P,
    const int* __restrict__ a1p, const int* __restrict__ a2p, const int* __restrict__ a3p,
    const int* __restrict__ a4p, const int* __restrict__ a5p, const int* __restrict__ a6p,
    u16* __restrict__ out)
{
  const int tid = threadIdx.x;
  const int rb = blockIdx.x * 128;
  int d, off; seg_of(rb, d, off);
  const int lane = tid & 63;
  const int nl = lane & 15;
  const int q  = lane >> 4;
  const int wvid = tid >> 6;

  bf8v bfrag[2][2];
  #pragma unroll
  for (int ks = 0; ks < 2; ++ks)
    #pragma unroll
    for (int ct = 0; ct < 2; ++ct)
      bfrag[ks][ct] = *(const bf8v*)(wf2 + (size_t)(((d * 2 + ks) * 2 + ct) * 64 + lane) * 8);

  const int r0 = rb + wvid * 32 + nl;
  const int r1 = r0 + 16;
  bf8v a0[2], a1f[2];
  switch (d) {
    case 0: gather2_conv2<0>(in, a1p, r0, r1, off, q, a0, a1f); break;
    case 1: gather2_conv2<1>(in, a1p, r0, r1, off, q, a0, a1f); break;
    case 2: gather2_conv2<2>(in, a2p, r0, r1, off, q, a0, a1f); break;
    case 3: gather2_conv2<3>(in, a3p, r0, r1, off, q, a0, a1f); break;
    case 4: gather2_conv2<4>(in, a4p, r0, r1, off, q, a0, a1f); break;
    case 5: gather2_conv2<5>(in, a5p, r0, r1, off, q, a0, a1f); break;
    default: gather2_conv2<6>(in, a6p, r0, r1, off, q, a0, a1f); break;
  }

  f32x4 acc[2][2] = {{{0,0,0,0},{0,0,0,0}},{{0,0,0,0},{0,0,0,0}}};
  #pragma unroll
  for (int ks = 0; ks < 2; ++ks) {
    acc[0][0] = __builtin_amdgcn_mfma_f32_16x16x32_bf16(a0[ks],  bfrag[ks][0], acc[0][0], 0, 0, 0);
    acc[0][1] = __builtin_amdgcn_mfma_f32_16x16x32_bf16(a0[ks],  bfrag[ks][1], acc[0][1], 0, 0, 0);
    acc[1][0] = __builtin_amdgcn_mfma_f32_16x16x32_bf16(a1f[ks], bfrag[ks][0], acc[1][0], 0, 0, 0);
    acc[1][1] = __builtin_amdgcn_mfma_f32_16x16x32_bf16(a1f[ks], bfrag[ks][1], acc[1][1], 0, 0, 0);
  }

  #pragma unroll
  for (int ct = 0; ct < 2; ++ct) {
    const int col = ct * 16 + nl;
    const float bias = P[P_EP2 + d * 32 + col];
    const float g  = P[P_BN1 + col];
    const float be = P[P_BN1 + 32 + col];
    const float mn = P[P_BN1 + 64 + col];
    const float iv = P[P_BN1 + 96 + col];
    #pragma unroll
    for (int t = 0; t < 2; ++t) {
      #pragma unroll
      for (int reg = 0; reg < 4; ++reg) {
        int row = rb + wvid * 32 + t * 16 + q * 4 + reg;
        float v = tanh_fast(acc[t][ct][reg] + bias);
        out[(size_t)row * 32 + col] = f2b(g * (v - mn) * iv + be);
      }
    }
  }
}

// ---------------- graph pool: 1 thread per 8 channels, all loads upfront
template<int D>
__device__ __forceinline__ void pool_one(
    const u16* __restrict__ in, const int* __restrict__ adjp,
    int r, int off, int q8, u16* __restrict__ out)
{
  constexpr int DD = (D > 0) ? D : 1;
  int nb[DD];
  if (D > 0) {
    size_t ib = (size_t)(r - off) * D;
    #pragma unroll
    for (int j = 0; j < D; ++j) nb[j] = adjp[ib + j];
  }
  uint4 sv = *(const uint4*)(in + (size_t)r * 32 + q8);
  uint4 nv[DD];
  #pragma unroll
  for (int j = 0; j < D; ++j) nv[j] = *(const uint4*)(in + (size_t)nb[j] * 32 + q8);
  union { uint4 u4; u16 us[8]; } s; s.u4 = sv;
  float v[8];
  #pragma unroll
  for (int i = 0; i < 8; ++i) v[i] = b2f(s.us[i]);
  #pragma unroll
  for (int j = 0; j < D; ++j) {
    union { uint4 u4; u16 us[8]; } a; a.u4 = nv[j];
    #pragma unroll
    for (int i = 0; i < 8; ++i) v[i] = fmaxf(v[i], b2f(a.us[i]));
  }
  union { uint4 u4; u16 us[8]; } o;
  #pragma unroll
  for (int i = 0; i < 8; ++i) o.us[i] = f2b(v[i]);
  *(uint4*)(out + (size_t)r * 32 + q8) = o.u4;
}

__global__ __launch_bounds__(256) void pool_kernel(
    const u16* __restrict__ in, u16* __restrict__ out,
    const int* __restrict__ a1, const int* __restrict__ a2, const int* __restrict__ a3,
    const int* __restrict__ a4, const int* __restrict__ a5, const int* __restrict__ a6)
{
  int idx = blockIdx.x * 256 + threadIdx.x;   // N_ATOMS*4 threads
  int r = idx >> 2, q8 = (idx & 3) * 8;
  int d, off; seg_of(r, d, off);
  switch (d) {
    case 0: pool_one<0>(in, a1, r, off, q8, out); break;
    case 1: pool_one<1>(in, a1, r, off, q8, out); break;
    case 2: pool_one<2>(in, a2, r, off, q8, out); break;
    case 3: pool_one<3>(in, a3, r, off, q8, out); break;
    case 4: pool_one<4>(in, a4, r, off, q8, out); break;
    case 5: pool_one<5>(in, a5, r, off, q8, out); break;
    default: pool_one<6>(in, a6, r, off, q8, out); break;
  }
}

// ---------------- head: 4 molecules per 256-thread block, precomputed tables
__global__ __launch_bounds__(256) void head_kernel(
    const u16* __restrict__ in, const float* __restrict__ P,
    const void* __restrict__ xadd, const int* flagp, void* __restrict__ outp)
{
  __shared__ __align__(16) float sA[4][1024];
  const int isbf = flagp[0];
  const int wvid = threadIdx.x >> 6;
  const int m = blockIdx.x * 4 + wvid;
  const int j = threadIdx.x & 63;

  #pragma unroll
  for (int ii = 0; ii < 2; ++ii) {
    int i = j + ii * 64;
    int t = i >> 2, kq8 = (i & 3) * 8;
    union { uint4 u4; u16 us[8]; } w;
    w.u4 = *(const uint4*)(in + (size_t)(m + t * 16384) * 32 + kq8);
    #pragma unroll
    for (int x = 0; x < 8; ++x) sA[wvid][t * 32 + kq8 + x] = b2f(w.us[x]);
  }
  __syncthreads();

  float wcol[32];
  const f32x4* wt4 = (const f32x4*)(P + P_D1WT + j * 32);
  #pragma unroll
  for (int k4 = 0; k4 < 8; ++k4) {
    f32x4 w4 = wt4[k4];
    wcol[k4 * 4] = w4[0]; wcol[k4 * 4 + 1] = w4[1];
    wcol[k4 * 4 + 2] = w4[2]; wcol[k4 * 4 + 3] = w4[3];
  }
  const float bj = P[P_D1B + j];
  const float g  = P[P_BN3 + j];
  const float bt = P[P_BN3 + 64 + j];
  const float mn = P[P_BN3 + 128 + j];
  const float iv = P[P_BN3 + 192 + j];

  float sum = 0.f, mx = -1e30f;
  for (int t = 0; t < 32; ++t) {
    const f32x4* arow = (const f32x4*)(&sA[wvid][t * 32]);
    float dot = bj;
    #pragma unroll
    for (int k4 = 0; k4 < 8; ++k4) {
      f32x4 av = arow[k4];
      dot += av[0] * wcol[k4 * 4]     + av[1] * wcol[k4 * 4 + 1]
           + av[2] * wcol[k4 * 4 + 2] + av[3] * wcol[k4 * 4 + 3];
    }
    float h  = tanh_fast(dot);
    float hb = g * (h - mn) * iv + bt;
    sum += hb;
    mx = fmaxf(mx, hb);
  }

  float part = tanh_fast(sum) * P[P_D2W + j] + tanh_fast(mx) * P[P_D2W + 64 + j];
  #pragma unroll
  for (int o = 32; o > 0; o >>= 1) part += __shfl_down(part, o, 64);

  if (j == 0) {
    float mv  = part + P[P_SC];
    float ans = mv * P[P_SC + 1] + P[P_SC + 17];
    #pragma unroll
    for (int i = 0; i < 15; ++i) ans += ldf(xadd, m * 15 + i, isbf) * P[P_SC + 2 + i];
    if (isbf) ((u16*)outp)[m] = f2b(ans);
    else      ((float*)outp)[m] = ans;
  }
}

extern "C" void kernel_launch(void* const* d_in, const int* in_sizes, int n_in,
                              void* d_out, int out_size, void* d_ws, size_t ws_size,
                              hipStream_t stream)
{
  (void)in_sizes; (void)n_in; (void)out_size;
  const void* atoms = d_in[0];
  const int* a1 = (const int*)d_in[2];
  const int* a2 = (const int*)d_in[3];
  const int* a3 = (const int*)d_in[4];
  const int* a4 = (const int*)d_in[5];
  const int* a5 = (const int*)d_in[6];
  const int* a6 = (const int*)d_in[7];

  char* ws = (char*)d_ws;
  int*  flag = (int*)ws;
  float* P   = (float*)(ws + 256);
  u16*  wf1  = (u16*)(ws + 16384);
  u16*  wf2  = (u16*)(ws + 88064);
  u16*  buf0 = (u16*)(ws + 131072);             // 32 MB

  const size_t need = 131072 + (size_t)NROW32 * 2 + (size_t)N_ATOMS * 80 * 2;
  const bool fast = ws_size >= need;

  probe_kernel<<<1, 64, 0, stream>>>(atoms, flag);
  prep_kernel<<<8, 64, 0, stream>>>(d_in[8], d_in[9], d_in[10], d_in[11],
                                    d_in[12], d_in[13], d_in[14], d_in[15],
                                    d_in[16], d_in[17], d_in[18], d_in[19],
                                    d_in[20], d_in[21], d_in[22], d_in[23],
                                    d_in[24], d_in[25], flag, ws);

  u16* buf1;
  if (fast) {
    u16* atomsB = buf0 + NROW32;                // 84 MB region
    buf1 = atomsB;                              // aliased: atomsB dead after conv1
    convert_kernel<<<4096, 256, 0, stream>>>(atoms, flag, atomsB);
    conv1_fast_kernel<<<4096, 256, 0, stream>>>(atomsB, wf1, P,
                                                a1, a2, a3, a4, a5, a6, buf0);
  } else {
    buf1 = buf0 + NROW32;
    conv1_slow_kernel<<<8192, 256, 0, stream>>>(atoms, d_in[8], d_in[9], d_in[12],
                                                d_in[13], d_in[14], d_in[15],
                                                a1, a2, a3, a4, a5, a6, flag, buf0);
  }

  pool_kernel<<<8192, 256, 0, stream>>>(buf0, buf1, a1, a2, a3, a4, a5, a6);
  conv2_kernel<<<4096, 256, 0, stream>>>(buf1, wf2, P, a1, a2, a3, a4, a5, a6, buf0);
  pool_kernel<<<8192, 256, 0, stream>>>(buf0, buf1, a1, a2, a3, a4, a5, a6);
  head_kernel<<<4096, 256, 0, stream>>>(buf1, P, d_in[26], flag, d_out);
}